// Round 6
// baseline (663.299 us; speedup 1.0000x reference)
//
#include <hip/hip_runtime.h>
#include <stdint.h>

#define D 768
#define FCH 16     // filter chunks per query
#define CPC 16     // candidates kept per chunk
#define NCAND 256  // FCH * CPC

typedef __bf16 bf16x8 __attribute__((ext_vector_type(8)));
typedef float  f32x4  __attribute__((ext_vector_type(4)));

static __device__ __forceinline__ float b2f(unsigned short u){
    union { unsigned int i; float f; } v; v.i = ((unsigned int)u) << 16; return v.f;
}
static __device__ __forceinline__ unsigned short f2b(float f){
    union { float f; unsigned int i; } v; v.f = f;
    unsigned int u = v.i;
    unsigned int r = (u + 0x7fffu + ((u >> 16) & 1u)) >> 16;
    return (unsigned short)r;
}
static __device__ __forceinline__ void gload_lds16(const void* g, void* l){
    __builtin_amdgcn_global_load_lds((const __attribute__((address_space(1))) void*)g,
                                     (__attribute__((address_space(3))) void*)l, 16, 0, 0);
}

// ---------------- elementwise f32 -> bf16 ----------------
__global__ __launch_bounds__(256) void cvt_kernel(const float* __restrict__ x,
                                                  unsigned short* __restrict__ y, size_t n){
    size_t i = ((size_t)blockIdx.x * 256 + threadIdx.x) * 4;
    if (i + 3 < n){
        f32x4 v = *(const f32x4*)(x + i);
        ushort4 o;
        o.x = f2b(v[0]); o.y = f2b(v[1]); o.z = f2b(v[2]); o.w = f2b(v[3]);
        *(ushort4*)(y + i) = o;
    }
}

// ---------------- W [D][D] f32 -> Wt [n][k] bf16 ----------------
__global__ __launch_bounds__(256) void transposeW(const float* __restrict__ W,
                                                  unsigned short* __restrict__ Wt){
    __shared__ unsigned short tile[32][33];
    int bx = blockIdx.x * 32;   // k base
    int by = blockIdx.y * 32;   // n base
    int tx = threadIdx.x & 31, ty = threadIdx.x >> 5;   // ty 0..7
    #pragma unroll
    for (int r = 0; r < 32; r += 8)
        tile[ty + r][tx] = f2b(W[(size_t)(bx + ty + r) * D + by + tx]);
    __syncthreads();
    #pragma unroll
    for (int r = 0; r < 32; r += 8)
        Wt[(size_t)(by + ty + r) * D + bx + tx] = tile[tx][ty + r];
}

// ---------------- degree / dis / CSR ----------------
__global__ __launch_bounds__(256) void deg_init(int* deg, int N){
    int i = blockIdx.x * 256 + threadIdx.x;
    if (i < N) deg[i] = 1;            // self loop
}
__global__ __launch_bounds__(256) void deg_count(const int* __restrict__ dst, int* deg, int E){
    int e = blockIdx.x * 256 + threadIdx.x;
    if (e < E) atomicAdd(&deg[dst[e]], 1);
}
__global__ __launch_bounds__(256) void dis_kernel(const int* __restrict__ deg, float* dis, int N){
    int i = blockIdx.x * 256 + threadIdx.x;
    if (i < N) dis[i] = rsqrtf((float)deg[i]);
}
__global__ __launch_bounds__(256) void blocksum_k(const int* __restrict__ deg, int* bsum, int N){
    __shared__ int sm[256];
    int tid = threadIdx.x;
    int i = blockIdx.x * 256 + tid;
    sm[tid] = (i < N) ? (deg[i] - 1) : 0;
    __syncthreads();
    for (int o = 128; o > 0; o >>= 1){
        if (tid < o) sm[tid] += sm[tid + o];
        __syncthreads();
    }
    if (tid == 0) bsum[blockIdx.x] = sm[0];
}
__global__ __launch_bounds__(256) void scanb_k(const int* __restrict__ bsum, int* boff, int nb){
    __shared__ int sm[256];
    int tid = threadIdx.x;
    int v = (tid < nb) ? bsum[tid] : 0;
    sm[tid] = v;
    __syncthreads();
    for (int o = 1; o < 256; o <<= 1){
        int add = (tid >= o) ? sm[tid - o] : 0;
        __syncthreads();
        sm[tid] += add;
        __syncthreads();
    }
    if (tid < nb) boff[tid] = sm[tid] - v;   // exclusive
}
__global__ __launch_bounds__(256) void scanfin_k(const int* __restrict__ deg,
                                                 const int* __restrict__ boff,
                                                 int* start, int N, int E){
    __shared__ int sm[256];
    int tid = threadIdx.x;
    int i = blockIdx.x * 256 + tid;
    int v = (i < N) ? (deg[i] - 1) : 0;
    sm[tid] = v;
    __syncthreads();
    for (int o = 1; o < 256; o <<= 1){
        int add = (tid >= o) ? sm[tid - o] : 0;
        __syncthreads();
        sm[tid] += add;
        __syncthreads();
    }
    if (i < N) start[i] = boff[blockIdx.x] + sm[tid] - v;
    if (i == 0) start[N] = E;
}
__global__ __launch_bounds__(256) void csr_fill(const int* __restrict__ src,
                                                const int* __restrict__ dst,
                                                const float* __restrict__ dis,
                                                const int* __restrict__ start,
                                                int* fill, int* csr_src, float* csr_norm, int E){
    int e = blockIdx.x * 256 + threadIdx.x;
    if (e >= E) return;
    int s = src[e], d = dst[e];
    int pos = atomicAdd(&fill[d], 1);
    int idx = start[d] + pos;
    csr_src[idx]  = s;
    csr_norm[idx] = dis[s] * dis[d];
}

// ---------------- bf16 MFMA GEMM: C[M][768] = A[M][768] @ W, Bt[n][k] = W[k][n] ----------------
// 1-D grid, XCD-chunked bijective swizzle (m204), n-tile innermost -> per-XCD L2 reuse of A-tile.
// Staging via global_load_lds width=16 into linear [128][32] LDS tiles.
__global__ __launch_bounds__(256) void gemm_bf16(const unsigned short* __restrict__ A,
                                                 const unsigned short* __restrict__ Bt,
                                                 unsigned short* __restrict__ C,
                                                 int M, int nTilesN){
    __shared__ unsigned short Al[128 * 32];
    __shared__ unsigned short Bl[128 * 32];
    const int nwg = gridDim.x;
    const int bid = blockIdx.x;
    const int q = nwg >> 3, r = nwg & 7;
    const int xcd = bid & 7, loc = bid >> 3;
    const int swz = (xcd < r ? xcd * (q + 1) : r * (q + 1) + (xcd - r) * q) + loc;
    const int mt = swz / nTilesN, nt = swz % nTilesN;
    const int m0 = mt * 128, n0 = nt * 128;

    const int tid  = threadIdx.x;
    const int lane = tid & 63;
    const int w    = tid >> 6;
    const int wr = w >> 1, wc = w & 1;
    const int l15 = lane & 15;
    const int lg  = lane >> 4;     // 0..3

    // per-lane global element offsets for staging (row within tile, col-of-8)
    const int srow0 = (0 * 4 + w) * 16 + (lane >> 2);   // issue j=0: slot = w
    const int srow1 = (1 * 4 + w) * 16 + (lane >> 2);   // issue j=1: slot = 4+w
    const int scol  = (lane & 3) * 8;

    f32x4 acc[4][4] = {};

    for (int k0 = 0; k0 < D; k0 += 32){
        // ---- stage A,B via async global->LDS (wave-uniform LDS base + lane*16) ----
        gload_lds16(A  + (size_t)(m0 + srow0) * D + k0 + scol, (char*)Al + (0 * 4 + w) * 1024);
        gload_lds16(A  + (size_t)(m0 + srow1) * D + k0 + scol, (char*)Al + (1 * 4 + w) * 1024);
        gload_lds16(Bt + (size_t)(n0 + srow0) * D + k0 + scol, (char*)Bl + (0 * 4 + w) * 1024);
        gload_lds16(Bt + (size_t)(n0 + srow1) * D + k0 + scol, (char*)Bl + (1 * 4 + w) * 1024);
        __syncthreads();
        bf16x8 af[4], bfv[4];
        #pragma unroll
        for (int mf = 0; mf < 4; mf++)
            af[mf] = *(const bf16x8*)(&Al[(wr * 64 + mf * 16 + l15) * 32 + lg * 8]);
        #pragma unroll
        for (int nf = 0; nf < 4; nf++)
            bfv[nf] = *(const bf16x8*)(&Bl[(wc * 64 + nf * 16 + l15) * 32 + lg * 8]);
        #pragma unroll
        for (int mf = 0; mf < 4; mf++)
            #pragma unroll
            for (int nf = 0; nf < 4; nf++)
                acc[mf][nf] = __builtin_amdgcn_mfma_f32_16x16x32_bf16(af[mf], bfv[nf], acc[mf][nf], 0, 0, 0);
        __syncthreads();
    }
    #pragma unroll
    for (int mf = 0; mf < 4; mf++){
        #pragma unroll
        for (int r2 = 0; r2 < 4; r2++){
            int gr = m0 + wr * 64 + mf * 16 + lg * 4 + r2;
            if (gr < M){
                #pragma unroll
                for (int nf = 0; nf < 4; nf++){
                    int gc = n0 + wc * 64 + nf * 16 + l15;
                    C[(size_t)gr * D + gc] = f2b(acc[mf][nf][r2]);
                }
            }
        }
    }
}

// ---------------- GCN aggregation: out[v] = (sum_e h[src]*norm) + h[v]*dis^2 + bias, opt relu ----
// One wave per node. Edge loop unrolled x4 for MLP (12 independent 8B loads in flight).
// Output written with nontemporal stores to avoid evicting h from L3 (h is the hot reuse set).
__global__ __launch_bounds__(256) void agg_kernel(const unsigned short* __restrict__ h,
                                                  unsigned short* __restrict__ out,
                                                  const int* __restrict__ start,
                                                  const int* __restrict__ csr_src,
                                                  const float* __restrict__ csr_norm,
                                                  const float* __restrict__ dis,
                                                  const float* __restrict__ bias,
                                                  int doRelu, int N){
    int wid = blockIdx.x * 4 + (threadIdx.x >> 6);
    if (wid >= N) return;
    int lane = threadIdx.x & 63;
    float acc[12];
    float dn = dis[wid];
    float sn = dn * dn;
    const unsigned short* hr = h + (size_t)wid * D + lane * 4;
    #pragma unroll
    for (int j = 0; j < 3; j++){
        ushort4 v = *(const ushort4*)(hr + 256 * j);
        acc[j*4+0] = b2f(v.x) * sn;
        acc[j*4+1] = b2f(v.y) * sn;
        acc[j*4+2] = b2f(v.z) * sn;
        acc[j*4+3] = b2f(v.w) * sn;
    }
    int e0 = start[wid], e1 = start[wid + 1];
    int e = e0;
    for (; e + 4 <= e1; e += 4){
        int   s[4]; float nm[4];
        #pragma unroll
        for (int b = 0; b < 4; b++){ s[b] = csr_src[e + b]; nm[b] = csr_norm[e + b]; }
        ushort4 v[4][3];
        #pragma unroll
        for (int b = 0; b < 4; b++){
            const unsigned short* hs = h + (size_t)s[b] * D + lane * 4;
            #pragma unroll
            for (int j = 0; j < 3; j++) v[b][j] = *(const ushort4*)(hs + 256 * j);
        }
        #pragma unroll
        for (int b = 0; b < 4; b++){
            #pragma unroll
            for (int j = 0; j < 3; j++){
                acc[j*4+0] += b2f(v[b][j].x) * nm[b];
                acc[j*4+1] += b2f(v[b][j].y) * nm[b];
                acc[j*4+2] += b2f(v[b][j].z) * nm[b];
                acc[j*4+3] += b2f(v[b][j].w) * nm[b];
            }
        }
    }
    for (; e < e1; e++){
        int s = csr_src[e];
        float nm = csr_norm[e];
        const unsigned short* hs = h + (size_t)s * D + lane * 4;
        #pragma unroll
        for (int j = 0; j < 3; j++){
            ushort4 v = *(const ushort4*)(hs + 256 * j);
            acc[j*4+0] += b2f(v.x) * nm;
            acc[j*4+1] += b2f(v.y) * nm;
            acc[j*4+2] += b2f(v.z) * nm;
            acc[j*4+3] += b2f(v.w) * nm;
        }
    }
    unsigned short* orow = out + (size_t)wid * D + lane * 4;
    #pragma unroll
    for (int j = 0; j < 3; j++){
        float r[4];
        #pragma unroll
        for (int i = 0; i < 4; i++){
            float t = acc[j*4+i] + bias[lane * 4 + 256 * j + i];
            if (doRelu) t = fmaxf(t, 0.0f);
            r[i] = t;
        }
        unsigned long long packed =
            (unsigned long long)f2b(r[0]) |
            ((unsigned long long)f2b(r[1]) << 16) |
            ((unsigned long long)f2b(r[2]) << 32) |
            ((unsigned long long)f2b(r[3]) << 48);
        __builtin_nontemporal_store(packed, (unsigned long long*)(orow + 256 * j));
    }
}

// ---------------- approx bert score via MFMA: score[q][n] = sw*sparse + dot(Qb,Xb) ----------------
__global__ __launch_bounds__(256) void mfma_bert(const unsigned short* __restrict__ Qb,
                                                 const unsigned short* __restrict__ Xb,
                                                 const float* __restrict__ sparse,
                                                 const float* __restrict__ swp,
                                                 float* __restrict__ scoreOut,
                                                 int B, int N){
    __shared__ unsigned short Al[64][40];
    __shared__ unsigned short Bl[128][40];
    const int tid  = threadIdx.x;
    const int lane = tid & 63;
    const int w    = tid >> 6;     // 0..3 n-quadrant
    const int l15  = lane & 15;
    const int lg   = lane >> 4;
    const int n0   = blockIdx.x * 128;

    f32x4 acc[4][2] = {};

    for (int k0 = 0; k0 < D; k0 += 32){
        {
            int row = tid >> 2;            // 0..63
            int ko  = (tid & 3) * 8;
            uint4 av = {0u,0u,0u,0u};
            if (row < B) av = *(const uint4*)(Qb + (size_t)row * D + k0 + ko);
            *(uint4*)(&Al[row][ko]) = av;
        }
        #pragma unroll
        for (int j = 0; j < 2; j++){
            int i   = tid + j * 256;
            int row = i >> 2;              // 0..127
            int ko  = (i & 3) * 8;
            int gn  = n0 + row;
            uint4 bv = {0u,0u,0u,0u};
            if (gn < N) bv = *(const uint4*)(Xb + (size_t)gn * D + k0 + ko);
            *(uint4*)(&Bl[row][ko]) = bv;
        }
        __syncthreads();
        bf16x8 af[4], bfv[2];
        #pragma unroll
        for (int mf = 0; mf < 4; mf++)
            af[mf] = *(const bf16x8*)(&Al[mf * 16 + l15][lg * 8]);
        #pragma unroll
        for (int nf = 0; nf < 2; nf++)
            bfv[nf] = *(const bf16x8*)(&Bl[w * 32 + nf * 16 + l15][lg * 8]);
        #pragma unroll
        for (int mf = 0; mf < 4; mf++)
            #pragma unroll
            for (int nf = 0; nf < 2; nf++)
                acc[mf][nf] = __builtin_amdgcn_mfma_f32_16x16x32_bf16(af[mf], bfv[nf], acc[mf][nf], 0, 0, 0);
        __syncthreads();
    }
    float sw = swp[0];
    #pragma unroll
    for (int mf = 0; mf < 4; mf++){
        #pragma unroll
        for (int nf = 0; nf < 2; nf++){
            #pragma unroll
            for (int r = 0; r < 4; r++){
                int q = mf * 16 + lg * 4 + r;
                int n = n0 + w * 32 + nf * 16 + l15;
                if (q < B && n < N)
                    scoreOut[(size_t)q * N + n] = sw * sparse[(size_t)q * N + n] + acc[mf][nf][r];
            }
        }
    }
}

// ---------------- filter: per-(query,chunk) local top-CPC by approx score ----------------
__global__ __launch_bounds__(256) void filter_topc(const float* __restrict__ score,
                                                   int* __restrict__ candIdx,
                                                   int N, int chunk){
    int b = blockIdx.y, g = blockIdx.x, tid = threadIdx.x;
    int base = g * chunk;
    const float* s = score + (size_t)b * N;
    extern __shared__ float vals[];
    for (int i = tid; i < chunk; i += 256){
        int n = base + i;
        vals[i] = (n < N) ? s[n] : -3.0e38f;
    }
    __shared__ float wv[4];
    __shared__ int   wsl[4];
    __syncthreads();
    int lane = tid & 63, wid = tid >> 6;
    int* out = candIdx + ((size_t)b * gridDim.x + g) * CPC;
    for (int it = 0; it < CPC; it++){
        float best = -3.0e38f; int bs = 0x7fffffff;
        for (int i = tid; i < chunk; i += 256){
            float v = vals[i];
            if (v > best){ best = v; bs = i; }
        }
        #pragma unroll
        for (int o = 32; o > 0; o >>= 1){
            float v2 = __shfl_down(best, o);
            int   s2 = __shfl_down(bs, o);
            if (v2 > best || (v2 == best && s2 < bs)){ best = v2; bs = s2; }
        }
        if (lane == 0){ wv[wid] = best; wsl[wid] = bs; }
        __syncthreads();
        if (tid == 0){
            float bv = wv[0]; int bi = wsl[0];
            #pragma unroll
            for (int w2 = 1; w2 < 4; w2++)
                if (wv[w2] > bv || (wv[w2] == bv && wsl[w2] < bi)){ bv = wv[w2]; bi = wsl[w2]; }
            out[it] = base + bi;
            if (bi >= 0 && bi < chunk) vals[bi] = -3.0e38f;
        }
        __syncthreads();
    }
}

// ---------------- exact fp32 rescore of NCAND candidates per query ----------------
__global__ __launch_bounds__(256) void rescore_kernel(const float* __restrict__ Q,
                                                      const float* __restrict__ X,
                                                      const float* __restrict__ sparse,
                                                      const float* __restrict__ swp,
                                                      const int* __restrict__ candIdx,
                                                      float* __restrict__ resVal,
                                                      int N){
    int b = blockIdx.y;
    int c0 = blockIdx.x * 64;
    int lane = threadIdx.x & 63, w = threadIdx.x >> 6;
    const float* q = Q + (size_t)b * D;
    f32x4 qv[3];
    #pragma unroll
    for (int j = 0; j < 3; j++) qv[j] = *(const f32x4*)(q + lane * 4 + 256 * j);
    float sw = swp[0];
    for (int t = 0; t < 16; t++){
        int ci = c0 + w * 16 + t;
        int n = candIdx[(size_t)b * NCAND + ci];
        const float* x = X + (size_t)n * D;
        float sum = 0.0f;
        #pragma unroll
        for (int j = 0; j < 3; j++){
            f32x4 xv = *(const f32x4*)(x + lane * 4 + 256 * j);
            sum += qv[j][0]*xv[0] + qv[j][1]*xv[1] + qv[j][2]*xv[2] + qv[j][3]*xv[3];
        }
        #pragma unroll
        for (int o = 32; o > 0; o >>= 1) sum += __shfl_down(sum, o);
        if (lane == 0)
            resVal[(size_t)b * NCAND + ci] = sw * sparse[(size_t)b * N + n] + sum;
    }
}

// ---------------- exact top-K among NCAND rescored (lax.top_k ties) + gold forcing ----------------
__global__ __launch_bounds__(256) void select_topk(const float* __restrict__ resVal,
                                                   const int* __restrict__ candIdx,
                                                   const int* __restrict__ qidx,
                                                   int* __restrict__ cand,
                                                   float* __restrict__ outIdx,
                                                   int K){
    int b = blockIdx.x, tid = threadIdx.x;
    __shared__ float vals[NCAND];
    __shared__ int   gidx[NCAND];
    __shared__ int   csel[64];
    __shared__ float wv[4];
    __shared__ int   wi[4];
    __shared__ int   wsl[4];
    vals[tid] = resVal[(size_t)b * NCAND + tid];
    gidx[tid] = candIdx[(size_t)b * NCAND + tid];
    __syncthreads();
    int lane = tid & 63, wid = tid >> 6;
    for (int it = 0; it < K; it++){
        float best = vals[tid]; int bg = gidx[tid]; int bsl = tid;
        #pragma unroll
        for (int o = 32; o > 0; o >>= 1){
            float v2 = __shfl_down(best, o);
            int   g2 = __shfl_down(bg, o);
            int   s2 = __shfl_down(bsl, o);
            if (v2 > best || (v2 == best && g2 < bg)){ best = v2; bg = g2; bsl = s2; }
        }
        if (lane == 0){ wv[wid] = best; wi[wid] = bg; wsl[wid] = bsl; }
        __syncthreads();
        if (tid == 0){
            float bv = wv[0]; int bi = wi[0]; int sl = wsl[0];
            #pragma unroll
            for (int w2 = 1; w2 < 4; w2++)
                if (wv[w2] > bv || (wv[w2] == bv && wi[w2] < bi)){ bv = wv[w2]; bi = wi[w2]; sl = wsl[w2]; }
            csel[it] = bi;
            vals[sl] = -3.0e38f;
        }
        __syncthreads();
    }
    if (tid == 0){
        int qi = qidx[b];
        bool has = false;
        for (int k2 = 0; k2 < K; k2++) if (csel[k2] == qi) has = true;
        if (!has) csel[K - 1] = qi;
    }
    __syncthreads();
    if (tid < K){
        cand[b * K + tid]   = csel[tid];
        outIdx[b * K + tid] = (float)csel[tid];
    }
}

// ---------------- final scoring head: relu(dot([g[c], q], score_W) + b) ----------------
__global__ __launch_bounds__(256) void final_kernel(const unsigned short* __restrict__ emb,
                                                    const float* __restrict__ Q,
                                                    const int* __restrict__ cand,
                                                    const float* __restrict__ scoreW,
                                                    const float* __restrict__ scoreB,
                                                    float* __restrict__ out, int B, int K){
    int pair = blockIdx.x * 4 + (threadIdx.x >> 6);
    if (pair >= B * K) return;
    int lane = threadIdx.x & 63;
    int b = pair / K;
    int c = cand[pair];
    const unsigned short* g = emb + (size_t)c * D;
    const float* q = Q + (size_t)b * D;
    float sum = 0.0f;
    #pragma unroll
    for (int j = 0; j < 12; j++){
        int col = lane + 64 * j;
        sum += b2f(g[col]) * scoreW[col] + q[col] * scoreW[D + col];
    }
    #pragma unroll
    for (int o = 32; o > 0; o >>= 1) sum += __shfl_down(sum, o);
    if (lane == 0) out[pair] = fmaxf(sum + scoreB[0], 0.0f);
}

extern "C" void kernel_launch(void* const* d_in, const int* in_sizes, int n_in,
                              void* d_out, int out_size, void* d_ws, size_t ws_size,
                              hipStream_t stream){
    const float* q_emb   = (const float*)d_in[0];
    const float* x_emb   = (const float*)d_in[1];
    const float* sparse  = (const float*)d_in[2];
    const int*   q_idx   = (const int*)d_in[3];
    const int*   eidx    = (const int*)d_in[4];
    const float* sweight = (const float*)d_in[5];
    const float* W1      = (const float*)d_in[6];
    const float* b1      = (const float*)d_in[7];
    const float* W2      = (const float*)d_in[8];
    const float* b2      = (const float*)d_in[9];
    const float* scoreW  = (const float*)d_in[10];
    const float* scoreB  = (const float*)d_in[11];

    const int B = in_sizes[0] / D;
    const int N = in_sizes[1] / D;
    const int E = in_sizes[4] / 2;
    const int K = out_size / (2 * B);

    const int* esrc = eidx;
    const int* edst = eidx + E;

    char* ws = (char*)d_ws;
    size_t off = 0;
    auto alloc = [&](size_t bytes) -> char* {
        char* p = ws + off;
        off = (off + bytes + 255) & ~(size_t)255;
        return p;
    };
    unsigned short* bufX = (unsigned short*)alloc((size_t)N * D * 2);  // x bf16 (persistent)
    unsigned short* bufH = (unsigned short*)alloc((size_t)N * D * 2);  // h1, later h2w
    unsigned short* bufG = (unsigned short*)alloc((size_t)N * D * 2);  // g1, later final emb
    unsigned short* Qb   = (unsigned short*)alloc((size_t)B * D * 2);  // query bf16
    unsigned short* W1t  = (unsigned short*)alloc((size_t)D * D * 2);
    unsigned short* W2t  = (unsigned short*)alloc((size_t)D * D * 2);
    int*   deg   = (int*)alloc((size_t)N * 4);
    float* dis   = (float*)alloc((size_t)N * 4);
    int*   start = (int*)alloc((size_t)(N + 1) * 4);
    int*   fill  = (int*)alloc((size_t)N * 4);
    int*   bsum  = (int*)alloc(1024);
    int*   boff  = (int*)alloc(1024);
    int*   csrs  = (int*)alloc((size_t)E * 4);
    float* csrn  = (float*)alloc((size_t)E * 4);
    float* approxScore = (float*)alloc((size_t)B * N * 4);
    int*   candIdx = (int*)alloc((size_t)B * NCAND * 4);
    float* resVal  = (float*)alloc((size_t)B * NCAND * 4);
    int*   candBuf = (int*)alloc((size_t)B * K * 4);
    (void)ws_size; (void)n_in;

    float* outScore = (float*)d_out;
    float* outIdx   = outScore + (size_t)B * K;

    // 1. conversions
    size_t nx = (size_t)N * D;
    cvt_kernel<<<(unsigned)((nx / 4 + 255) / 256), 256, 0, stream>>>(x_emb, bufX, nx);
    size_t nq = (size_t)B * D;
    cvt_kernel<<<(unsigned)((nq / 4 + 255) / 256), 256, 0, stream>>>(q_emb, Qb, nq);
    dim3 tg(D / 32, D / 32);
    transposeW<<<tg, 256, 0, stream>>>(W1, W1t);
    transposeW<<<tg, 256, 0, stream>>>(W2, W2t);

    // 2. degree + CSR
    int nb = (N + 255) / 256;
    deg_init<<<nb, 256, 0, stream>>>(deg, N);
    deg_count<<<(E + 255) / 256, 256, 0, stream>>>(edst, deg, E);
    dis_kernel<<<nb, 256, 0, stream>>>(deg, dis, N);
    blocksum_k<<<nb, 256, 0, stream>>>(deg, bsum, N);
    scanb_k<<<1, 256, 0, stream>>>(bsum, boff, nb);
    scanfin_k<<<nb, 256, 0, stream>>>(deg, boff, start, N, E);
    hipMemsetAsync(fill, 0, (size_t)N * 4, stream);
    csr_fill<<<(E + 255) / 256, 256, 0, stream>>>(esrc, edst, dis, start, fill, csrs, csrn, E);

    // 3. GCN layer 1  (bufX -> bufH -> bufG)
    const int nTilesM = (N + 127) / 128;
    const int nTilesN = D / 128;             // 6
    const int gemmWG  = nTilesM * nTilesN;
    gemm_bf16<<<gemmWG, 256, 0, stream>>>(bufX, W1t, bufH, N, nTilesN);
    agg_kernel<<<(N + 3) / 4, 256, 0, stream>>>(bufH, bufG, start, csrs, csrn, dis, b1, 1, N);

    // 4. GCN layer 2  (bufG -> bufH -> bufG)   [bufX stays = x bf16]
    gemm_bf16<<<gemmWG, 256, 0, stream>>>(bufG, W2t, bufH, N, nTilesN);
    agg_kernel<<<(N + 3) / 4, 256, 0, stream>>>(bufH, bufG, start, csrs, csrn, dis, b2, 0, N);

    // 5. retrieval: bf16 MFMA approx scores -> chunked top-CPC filter -> exact fp32 rescore -> exact top-K
    mfma_bert<<<(N + 127) / 128, 256, 0, stream>>>(Qb, bufX, sparse, sweight, approxScore, B, N);
    int chunk = (N + FCH - 1) / FCH;
    dim3 fgrid(FCH, B);
    filter_topc<<<fgrid, 256, (size_t)chunk * 4, stream>>>(approxScore, candIdx, N, chunk);
    dim3 rgrid(NCAND / 64, B);
    rescore_kernel<<<rgrid, 256, 0, stream>>>(q_emb, x_emb, sparse, sweight, candIdx, resVal, N);
    select_topk<<<B, 256, 0, stream>>>(resVal, candIdx, q_idx, candBuf, outIdx, K);

    // 6. final scoring head  (embeddings now in bufG)
    final_kernel<<<(B * K + 3) / 4, 256, 0, stream>>>(bufG, q_emb, candBuf, scoreW, scoreB, outScore, B, K);
}

// Round 7
// 542.146 us; speedup vs baseline: 1.2235x; 1.2235x over previous
//
#include <hip/hip_runtime.h>
#include <stdint.h>

#define D 768
#define FCH 16     // filter chunks per query
#define CPC 16     // candidates kept per chunk
#define NCAND 256  // FCH * CPC

typedef __bf16 bf16x8 __attribute__((ext_vector_type(8)));
typedef float  f32x4  __attribute__((ext_vector_type(4)));
typedef float  f32x2  __attribute__((ext_vector_type(2)));

static __device__ __forceinline__ float b2f(unsigned short u){
    union { unsigned int i; float f; } v; v.i = ((unsigned int)u) << 16; return v.f;
}
static __device__ __forceinline__ unsigned short f2b(float f){
    union { float f; unsigned int i; } v; v.f = f;
    unsigned int u = v.i;
    unsigned int r = (u + 0x7fffu + ((u >> 16) & 1u)) >> 16;
    return (unsigned short)r;
}
static __device__ __forceinline__ void gload_lds16(const void* g, void* l){
    __builtin_amdgcn_global_load_lds((const __attribute__((address_space(1))) void*)g,
                                     (__attribute__((address_space(3))) void*)l, 16, 0, 0);
}
// decode 4 fp8 (OCP e4m3) packed in u, FMA into acc[0..3] with weight nm
static __device__ __forceinline__ void dec4_fma(unsigned int u, float nm, float* acc){
    f32x2 a = __builtin_amdgcn_cvt_pk_f32_fp8((int)u, false);
    f32x2 b = __builtin_amdgcn_cvt_pk_f32_fp8((int)u, true);
    acc[0] += a[0] * nm; acc[1] += a[1] * nm;
    acc[2] += b[0] * nm; acc[3] += b[1] * nm;
}
static __device__ __forceinline__ unsigned char f2fp8(float f){
    int p = __builtin_amdgcn_cvt_pk_fp8_f32(f, 0.0f, 0, false);
    return (unsigned char)(p & 0xFF);
}

// ---------------- elementwise f32 -> bf16 ----------------
__global__ __launch_bounds__(256) void cvt_kernel(const float* __restrict__ x,
                                                  unsigned short* __restrict__ y, size_t n){
    size_t i = ((size_t)blockIdx.x * 256 + threadIdx.x) * 4;
    if (i + 3 < n){
        f32x4 v = *(const f32x4*)(x + i);
        ushort4 o;
        o.x = f2b(v[0]); o.y = f2b(v[1]); o.z = f2b(v[2]); o.w = f2b(v[3]);
        *(ushort4*)(y + i) = o;
    }
}

// ---------------- W [D][D] f32 -> Wt [n][k] bf16 ----------------
__global__ __launch_bounds__(256) void transposeW(const float* __restrict__ W,
                                                  unsigned short* __restrict__ Wt){
    __shared__ unsigned short tile[32][33];
    int bx = blockIdx.x * 32;   // k base
    int by = blockIdx.y * 32;   // n base
    int tx = threadIdx.x & 31, ty = threadIdx.x >> 5;   // ty 0..7
    #pragma unroll
    for (int r = 0; r < 32; r += 8)
        tile[ty + r][tx] = f2b(W[(size_t)(bx + ty + r) * D + by + tx]);
    __syncthreads();
    #pragma unroll
    for (int r = 0; r < 32; r += 8)
        Wt[(size_t)(by + ty + r) * D + bx + tx] = tile[tx][ty + r];
}

// ---------------- degree / dis / CSR ----------------
__global__ __launch_bounds__(256) void deg_init(int* deg, int N){
    int i = blockIdx.x * 256 + threadIdx.x;
    if (i < N) deg[i] = 1;            // self loop
}
__global__ __launch_bounds__(256) void deg_count(const int* __restrict__ dst, int* deg, int E){
    int e = blockIdx.x * 256 + threadIdx.x;
    if (e < E) atomicAdd(&deg[dst[e]], 1);
}
__global__ __launch_bounds__(256) void dis_kernel(const int* __restrict__ deg, float* dis, int N){
    int i = blockIdx.x * 256 + threadIdx.x;
    if (i < N) dis[i] = rsqrtf((float)deg[i]);
}
__global__ __launch_bounds__(256) void blocksum_k(const int* __restrict__ deg, int* bsum, int N){
    __shared__ int sm[256];
    int tid = threadIdx.x;
    int i = blockIdx.x * 256 + tid;
    sm[tid] = (i < N) ? (deg[i] - 1) : 0;
    __syncthreads();
    for (int o = 128; o > 0; o >>= 1){
        if (tid < o) sm[tid] += sm[tid + o];
        __syncthreads();
    }
    if (tid == 0) bsum[blockIdx.x] = sm[0];
}
__global__ __launch_bounds__(256) void scanb_k(const int* __restrict__ bsum, int* boff, int nb){
    __shared__ int sm[256];
    int tid = threadIdx.x;
    int v = (tid < nb) ? bsum[tid] : 0;
    sm[tid] = v;
    __syncthreads();
    for (int o = 1; o < 256; o <<= 1){
        int add = (tid >= o) ? sm[tid - o] : 0;
        __syncthreads();
        sm[tid] += add;
        __syncthreads();
    }
    if (tid < nb) boff[tid] = sm[tid] - v;   // exclusive
}
__global__ __launch_bounds__(256) void scanfin_k(const int* __restrict__ deg,
                                                 const int* __restrict__ boff,
                                                 int* start, int N, int E){
    __shared__ int sm[256];
    int tid = threadIdx.x;
    int i = blockIdx.x * 256 + tid;
    int v = (i < N) ? (deg[i] - 1) : 0;
    sm[tid] = v;
    __syncthreads();
    for (int o = 1; o < 256; o <<= 1){
        int add = (tid >= o) ? sm[tid - o] : 0;
        __syncthreads();
        sm[tid] += add;
        __syncthreads();
    }
    if (i < N) start[i] = boff[blockIdx.x] + sm[tid] - v;
    if (i == 0) start[N] = E;
}
__global__ __launch_bounds__(256) void csr_fill(const int* __restrict__ src,
                                                const int* __restrict__ dst,
                                                const float* __restrict__ dis,
                                                const int* __restrict__ start,
                                                int* fill, int* csr_src, float* csr_norm, int E){
    int e = blockIdx.x * 256 + threadIdx.x;
    if (e >= E) return;
    int s = src[e], d = dst[e];
    int pos = atomicAdd(&fill[d], 1);
    int idx = start[d] + pos;
    csr_src[idx]  = s;
    csr_norm[idx] = dis[s] * dis[d];
}

// ---------------- bf16 MFMA GEMM: C = A[M][768] @ W. FP8OUT: C written as fp8 e4m3 ----------------
// 1-D grid, XCD-chunked bijective swizzle, n-tile innermost -> per-XCD L2 reuse of A-tile.
// Staging via global_load_lds width=16 into linear [128][32] LDS tiles.
template<bool FP8OUT>
__global__ __launch_bounds__(256) void gemm_bf16(const unsigned short* __restrict__ A,
                                                 const unsigned short* __restrict__ Bt,
                                                 void* __restrict__ Cout,
                                                 int M, int nTilesN){
    __shared__ unsigned short Al[128 * 32];
    __shared__ unsigned short Bl[128 * 32];
    const int nwg = gridDim.x;
    const int bid = blockIdx.x;
    const int q = nwg >> 3, r = nwg & 7;
    const int xcd = bid & 7, loc = bid >> 3;
    const int swz = (xcd < r ? xcd * (q + 1) : r * (q + 1) + (xcd - r) * q) + loc;
    const int mt = swz / nTilesN, nt = swz % nTilesN;
    const int m0 = mt * 128, n0 = nt * 128;

    const int tid  = threadIdx.x;
    const int lane = tid & 63;
    const int w    = tid >> 6;
    const int wr = w >> 1, wc = w & 1;
    const int l15 = lane & 15;
    const int lg  = lane >> 4;     // 0..3

    const int srow0 = (0 * 4 + w) * 16 + (lane >> 2);
    const int srow1 = (1 * 4 + w) * 16 + (lane >> 2);
    const int scol  = (lane & 3) * 8;

    f32x4 acc[4][4] = {};

    for (int k0 = 0; k0 < D; k0 += 32){
        gload_lds16(A  + (size_t)(m0 + srow0) * D + k0 + scol, (char*)Al + (0 * 4 + w) * 1024);
        gload_lds16(A  + (size_t)(m0 + srow1) * D + k0 + scol, (char*)Al + (1 * 4 + w) * 1024);
        gload_lds16(Bt + (size_t)(n0 + srow0) * D + k0 + scol, (char*)Bl + (0 * 4 + w) * 1024);
        gload_lds16(Bt + (size_t)(n0 + srow1) * D + k0 + scol, (char*)Bl + (1 * 4 + w) * 1024);
        __syncthreads();
        bf16x8 af[4], bfv[4];
        #pragma unroll
        for (int mf = 0; mf < 4; mf++)
            af[mf] = *(const bf16x8*)(&Al[(wr * 64 + mf * 16 + l15) * 32 + lg * 8]);
        #pragma unroll
        for (int nf = 0; nf < 4; nf++)
            bfv[nf] = *(const bf16x8*)(&Bl[(wc * 64 + nf * 16 + l15) * 32 + lg * 8]);
        #pragma unroll
        for (int mf = 0; mf < 4; mf++)
            #pragma unroll
            for (int nf = 0; nf < 4; nf++)
                acc[mf][nf] = __builtin_amdgcn_mfma_f32_16x16x32_bf16(af[mf], bfv[nf], acc[mf][nf], 0, 0, 0);
        __syncthreads();
    }
    #pragma unroll
    for (int mf = 0; mf < 4; mf++){
        #pragma unroll
        for (int r2 = 0; r2 < 4; r2++){
            int gr = m0 + wr * 64 + mf * 16 + lg * 4 + r2;
            if (gr < M){
                #pragma unroll
                for (int nf = 0; nf < 4; nf++){
                    int gc = n0 + wc * 64 + nf * 16 + l15;
                    if constexpr (FP8OUT)
                        ((unsigned char*)Cout)[(size_t)gr * D + gc] = f2fp8(acc[mf][nf][r2]);
                    else
                        ((unsigned short*)Cout)[(size_t)gr * D + gc] = f2b(acc[mf][nf][r2]);
                }
            }
        }
    }
}

// ---------------- GCN aggregation (fp8 gather): out[v] = sum h8[src]*norm + h8[v]*dis^2 + bias ----
// One wave per node; lane covers 12 consecutive dims [lane*12, lane*12+12).
// Gather reads 768 B/row (3x dword per lane), HW fp8->f32 decode, fp32 accumulate, bf16 out.
__global__ __launch_bounds__(256) void agg_fp8(const unsigned char* __restrict__ h8,
                                               unsigned short* __restrict__ out,
                                               const int* __restrict__ start,
                                               const int* __restrict__ csr_src,
                                               const float* __restrict__ csr_norm,
                                               const float* __restrict__ dis,
                                               const float* __restrict__ bias,
                                               int doRelu, int N){
    int wid = blockIdx.x * 4 + (threadIdx.x >> 6);
    if (wid >= N) return;
    int lane = threadIdx.x & 63;
    const int lo = lane * 12;
    float acc[12] = {};
    float dn = dis[wid];
    float sn = dn * dn;
    {
        const unsigned char* hr = h8 + (size_t)wid * D + lo;
        unsigned int u0 = *(const unsigned int*)(hr);
        unsigned int u1 = *(const unsigned int*)(hr + 4);
        unsigned int u2 = *(const unsigned int*)(hr + 8);
        dec4_fma(u0, sn, acc); dec4_fma(u1, sn, acc + 4); dec4_fma(u2, sn, acc + 8);
    }
    int e0 = start[wid], e1 = start[wid + 1];
    int e = e0;
    for (; e + 8 <= e1; e += 8){
        int s[8]; float nm[8]; unsigned int u[8][3];
        #pragma unroll
        for (int b = 0; b < 8; b++){ s[b] = csr_src[e + b]; nm[b] = csr_norm[e + b]; }
        #pragma unroll
        for (int b = 0; b < 8; b++){
            const unsigned char* hs = h8 + (size_t)s[b] * D + lo;
            u[b][0] = *(const unsigned int*)(hs);
            u[b][1] = *(const unsigned int*)(hs + 4);
            u[b][2] = *(const unsigned int*)(hs + 8);
        }
        #pragma unroll
        for (int b = 0; b < 8; b++){
            dec4_fma(u[b][0], nm[b], acc);
            dec4_fma(u[b][1], nm[b], acc + 4);
            dec4_fma(u[b][2], nm[b], acc + 8);
        }
    }
    for (; e < e1; e++){
        int s = csr_src[e];
        float nm = csr_norm[e];
        const unsigned char* hs = h8 + (size_t)s * D + lo;
        unsigned int u0 = *(const unsigned int*)(hs);
        unsigned int u1 = *(const unsigned int*)(hs + 4);
        unsigned int u2 = *(const unsigned int*)(hs + 8);
        dec4_fma(u0, nm, acc); dec4_fma(u1, nm, acc + 4); dec4_fma(u2, nm, acc + 8);
    }
    unsigned short* orow = out + (size_t)wid * D + lo;
    #pragma unroll
    for (int j = 0; j < 3; j++){
        float r[4];
        #pragma unroll
        for (int i = 0; i < 4; i++){
            float t = acc[j * 4 + i] + bias[lo + j * 4 + i];
            if (doRelu) t = fmaxf(t, 0.0f);
            r[i] = t;
        }
        unsigned long long packed =
            (unsigned long long)f2b(r[0]) |
            ((unsigned long long)f2b(r[1]) << 16) |
            ((unsigned long long)f2b(r[2]) << 32) |
            ((unsigned long long)f2b(r[3]) << 48);
        __builtin_nontemporal_store(packed, (unsigned long long*)(orow + j * 4));
    }
}

// ---------------- approx bert score via MFMA: score[q][n] = sw*sparse + dot(Qb,Xb) ----------------
__global__ __launch_bounds__(256) void mfma_bert(const unsigned short* __restrict__ Qb,
                                                 const unsigned short* __restrict__ Xb,
                                                 const float* __restrict__ sparse,
                                                 const float* __restrict__ swp,
                                                 float* __restrict__ scoreOut,
                                                 int B, int N){
    __shared__ unsigned short Al[64][40];
    __shared__ unsigned short Bl[128][40];
    const int tid  = threadIdx.x;
    const int lane = tid & 63;
    const int w    = tid >> 6;     // 0..3 n-quadrant
    const int l15  = lane & 15;
    const int lg   = lane >> 4;
    const int n0   = blockIdx.x * 128;

    f32x4 acc[4][2] = {};

    for (int k0 = 0; k0 < D; k0 += 32){
        {
            int row = tid >> 2;            // 0..63
            int ko  = (tid & 3) * 8;
            uint4 av = {0u,0u,0u,0u};
            if (row < B) av = *(const uint4*)(Qb + (size_t)row * D + k0 + ko);
            *(uint4*)(&Al[row][ko]) = av;
        }
        #pragma unroll
        for (int j = 0; j < 2; j++){
            int i   = tid + j * 256;
            int row = i >> 2;              // 0..127
            int ko  = (i & 3) * 8;
            int gn  = n0 + row;
            uint4 bv = {0u,0u,0u,0u};
            if (gn < N) bv = *(const uint4*)(Xb + (size_t)gn * D + k0 + ko);
            *(uint4*)(&Bl[row][ko]) = bv;
        }
        __syncthreads();
        bf16x8 af[4], bfv[2];
        #pragma unroll
        for (int mf = 0; mf < 4; mf++)
            af[mf] = *(const bf16x8*)(&Al[mf * 16 + l15][lg * 8]);
        #pragma unroll
        for (int nf = 0; nf < 2; nf++)
            bfv[nf] = *(const bf16x8*)(&Bl[w * 32 + nf * 16 + l15][lg * 8]);
        #pragma unroll
        for (int mf = 0; mf < 4; mf++)
            #pragma unroll
            for (int nf = 0; nf < 2; nf++)
                acc[mf][nf] = __builtin_amdgcn_mfma_f32_16x16x32_bf16(af[mf], bfv[nf], acc[mf][nf], 0, 0, 0);
        __syncthreads();
    }
    float sw = swp[0];
    #pragma unroll
    for (int mf = 0; mf < 4; mf++){
        #pragma unroll
        for (int nf = 0; nf < 2; nf++){
            #pragma unroll
            for (int r = 0; r < 4; r++){
                int q = mf * 16 + lg * 4 + r;
                int n = n0 + w * 32 + nf * 16 + l15;
                if (q < B && n < N)
                    scoreOut[(size_t)q * N + n] = sw * sparse[(size_t)q * N + n] + acc[mf][nf][r];
            }
        }
    }
}

// ---------------- filter: per-(query,chunk) local top-CPC by approx score ----------------
__global__ __launch_bounds__(256) void filter_topc(const float* __restrict__ score,
                                                   int* __restrict__ candIdx,
                                                   int N, int chunk){
    int b = blockIdx.y, g = blockIdx.x, tid = threadIdx.x;
    int base = g * chunk;
    const float* s = score + (size_t)b * N;
    extern __shared__ float vals[];
    for (int i = tid; i < chunk; i += 256){
        int n = base + i;
        vals[i] = (n < N) ? s[n] : -3.0e38f;
    }
    __shared__ float wv[4];
    __shared__ int   wsl[4];
    __syncthreads();
    int lane = tid & 63, wid = tid >> 6;
    int* out = candIdx + ((size_t)b * gridDim.x + g) * CPC;
    for (int it = 0; it < CPC; it++){
        float best = -3.0e38f; int bs = 0x7fffffff;
        for (int i = tid; i < chunk; i += 256){
            float v = vals[i];
            if (v > best){ best = v; bs = i; }
        }
        #pragma unroll
        for (int o = 32; o > 0; o >>= 1){
            float v2 = __shfl_down(best, o);
            int   s2 = __shfl_down(bs, o);
            if (v2 > best || (v2 == best && s2 < bs)){ best = v2; bs = s2; }
        }
        if (lane == 0){ wv[wid] = best; wsl[wid] = bs; }
        __syncthreads();
        if (tid == 0){
            float bv = wv[0]; int bi = wsl[0];
            #pragma unroll
            for (int w2 = 1; w2 < 4; w2++)
                if (wv[w2] > bv || (wv[w2] == bv && wsl[w2] < bi)){ bv = wv[w2]; bi = wsl[w2]; }
            out[it] = base + bi;
            if (bi >= 0 && bi < chunk) vals[bi] = -3.0e38f;
        }
        __syncthreads();
    }
}

// ---------------- exact fp32 rescore of NCAND candidates per query ----------------
__global__ __launch_bounds__(256) void rescore_kernel(const float* __restrict__ Q,
                                                      const float* __restrict__ X,
                                                      const float* __restrict__ sparse,
                                                      const float* __restrict__ swp,
                                                      const int* __restrict__ candIdx,
                                                      float* __restrict__ resVal,
                                                      int N){
    int b = blockIdx.y;
    int c0 = blockIdx.x * 64;
    int lane = threadIdx.x & 63, w = threadIdx.x >> 6;
    const float* q = Q + (size_t)b * D;
    f32x4 qv[3];
    #pragma unroll
    for (int j = 0; j < 3; j++) qv[j] = *(const f32x4*)(q + lane * 4 + 256 * j);
    float sw = swp[0];
    for (int t = 0; t < 16; t++){
        int ci = c0 + w * 16 + t;
        int n = candIdx[(size_t)b * NCAND + ci];
        const float* x = X + (size_t)n * D;
        float sum = 0.0f;
        #pragma unroll
        for (int j = 0; j < 3; j++){
            f32x4 xv = *(const f32x4*)(x + lane * 4 + 256 * j);
            sum += qv[j][0]*xv[0] + qv[j][1]*xv[1] + qv[j][2]*xv[2] + qv[j][3]*xv[3];
        }
        #pragma unroll
        for (int o = 32; o > 0; o >>= 1) sum += __shfl_down(sum, o);
        if (lane == 0)
            resVal[(size_t)b * NCAND + ci] = sw * sparse[(size_t)b * N + n] + sum;
    }
}

// ---------------- exact top-K among NCAND rescored (lax.top_k ties) + gold forcing ----------------
__global__ __launch_bounds__(256) void select_topk(const float* __restrict__ resVal,
                                                   const int* __restrict__ candIdx,
                                                   const int* __restrict__ qidx,
                                                   int* __restrict__ cand,
                                                   float* __restrict__ outIdx,
                                                   int K){
    int b = blockIdx.x, tid = threadIdx.x;
    __shared__ float vals[NCAND];
    __shared__ int   gidx[NCAND];
    __shared__ int   csel[64];
    __shared__ float wv[4];
    __shared__ int   wi[4];
    __shared__ int   wsl[4];
    vals[tid] = resVal[(size_t)b * NCAND + tid];
    gidx[tid] = candIdx[(size_t)b * NCAND + tid];
    __syncthreads();
    int lane = tid & 63, wid = tid >> 6;
    for (int it = 0; it < K; it++){
        float best = vals[tid]; int bg = gidx[tid]; int bsl = tid;
        #pragma unroll
        for (int o = 32; o > 0; o >>= 1){
            float v2 = __shfl_down(best, o);
            int   g2 = __shfl_down(bg, o);
            int   s2 = __shfl_down(bsl, o);
            if (v2 > best || (v2 == best && g2 < bg)){ best = v2; bg = g2; bsl = s2; }
        }
        if (lane == 0){ wv[wid] = best; wi[wid] = bg; wsl[wid] = bsl; }
        __syncthreads();
        if (tid == 0){
            float bv = wv[0]; int bi = wi[0]; int sl = wsl[0];
            #pragma unroll
            for (int w2 = 1; w2 < 4; w2++)
                if (wv[w2] > bv || (wv[w2] == bv && wi[w2] < bi)){ bv = wv[w2]; bi = wi[w2]; sl = wsl[w2]; }
            csel[it] = bi;
            vals[sl] = -3.0e38f;
        }
        __syncthreads();
    }
    if (tid == 0){
        int qi = qidx[b];
        bool has = false;
        for (int k2 = 0; k2 < K; k2++) if (csel[k2] == qi) has = true;
        if (!has) csel[K - 1] = qi;
    }
    __syncthreads();
    if (tid < K){
        cand[b * K + tid]   = csel[tid];
        outIdx[b * K + tid] = (float)csel[tid];
    }
}

// ---------------- final scoring head: relu(dot([g[c], q], score_W) + b) ----------------
__global__ __launch_bounds__(256) void final_kernel(const unsigned short* __restrict__ emb,
                                                    const float* __restrict__ Q,
                                                    const int* __restrict__ cand,
                                                    const float* __restrict__ scoreW,
                                                    const float* __restrict__ scoreB,
                                                    float* __restrict__ out, int B, int K){
    int pair = blockIdx.x * 4 + (threadIdx.x >> 6);
    if (pair >= B * K) return;
    int lane = threadIdx.x & 63;
    int b = pair / K;
    int c = cand[pair];
    const unsigned short* g = emb + (size_t)c * D;
    const float* q = Q + (size_t)b * D;
    float sum = 0.0f;
    #pragma unroll
    for (int j = 0; j < 12; j++){
        int col = lane + 64 * j;
        sum += b2f(g[col]) * scoreW[col] + q[col] * scoreW[D + col];
    }
    #pragma unroll
    for (int o = 32; o > 0; o >>= 1) sum += __shfl_down(sum, o);
    if (lane == 0) out[pair] = fmaxf(sum + scoreB[0], 0.0f);
}

extern "C" void kernel_launch(void* const* d_in, const int* in_sizes, int n_in,
                              void* d_out, int out_size, void* d_ws, size_t ws_size,
                              hipStream_t stream){
    const float* q_emb   = (const float*)d_in[0];
    const float* x_emb   = (const float*)d_in[1];
    const float* sparse  = (const float*)d_in[2];
    const int*   q_idx   = (const int*)d_in[3];
    const int*   eidx    = (const int*)d_in[4];
    const float* sweight = (const float*)d_in[5];
    const float* W1      = (const float*)d_in[6];
    const float* b1      = (const float*)d_in[7];
    const float* W2      = (const float*)d_in[8];
    const float* b2      = (const float*)d_in[9];
    const float* scoreW  = (const float*)d_in[10];
    const float* scoreB  = (const float*)d_in[11];

    const int B = in_sizes[0] / D;
    const int N = in_sizes[1] / D;
    const int E = in_sizes[4] / 2;
    const int K = out_size / (2 * B);

    const int* esrc = eidx;
    const int* edst = eidx + E;

    char* ws = (char*)d_ws;
    size_t off = 0;
    auto alloc = [&](size_t bytes) -> char* {
        char* p = ws + off;
        off = (off + bytes + 255) & ~(size_t)255;
        return p;
    };
    unsigned short* bufX = (unsigned short*)alloc((size_t)N * D * 2);  // x bf16 (persistent)
    unsigned char*  bufH8 = (unsigned char*)alloc((size_t)N * D);      // h fp8 (gemm out, agg in)
    unsigned short* bufG = (unsigned short*)alloc((size_t)N * D * 2);  // g1, later final emb
    unsigned short* Qb   = (unsigned short*)alloc((size_t)B * D * 2);  // query bf16
    unsigned short* W1t  = (unsigned short*)alloc((size_t)D * D * 2);
    unsigned short* W2t  = (unsigned short*)alloc((size_t)D * D * 2);
    int*   deg   = (int*)alloc((size_t)N * 4);
    float* dis   = (float*)alloc((size_t)N * 4);
    int*   start = (int*)alloc((size_t)(N + 1) * 4);
    int*   fill  = (int*)alloc((size_t)N * 4);
    int*   bsum  = (int*)alloc(1024);
    int*   boff  = (int*)alloc(1024);
    int*   csrs  = (int*)alloc((size_t)E * 4);
    float* csrn  = (float*)alloc((size_t)E * 4);
    float* approxScore = (float*)alloc((size_t)B * N * 4);
    int*   candIdx = (int*)alloc((size_t)B * NCAND * 4);
    float* resVal  = (float*)alloc((size_t)B * NCAND * 4);
    int*   candBuf = (int*)alloc((size_t)B * K * 4);
    (void)ws_size; (void)n_in;

    float* outScore = (float*)d_out;
    float* outIdx   = outScore + (size_t)B * K;

    // 1. conversions
    size_t nx = (size_t)N * D;
    cvt_kernel<<<(unsigned)((nx / 4 + 255) / 256), 256, 0, stream>>>(x_emb, bufX, nx);
    size_t nq = (size_t)B * D;
    cvt_kernel<<<(unsigned)((nq / 4 + 255) / 256), 256, 0, stream>>>(q_emb, Qb, nq);
    dim3 tg(D / 32, D / 32);
    transposeW<<<tg, 256, 0, stream>>>(W1, W1t);
    transposeW<<<tg, 256, 0, stream>>>(W2, W2t);

    // 2. degree + CSR
    int nb = (N + 255) / 256;
    deg_init<<<nb, 256, 0, stream>>>(deg, N);
    deg_count<<<(E + 255) / 256, 256, 0, stream>>>(edst, deg, E);
    dis_kernel<<<nb, 256, 0, stream>>>(deg, dis, N);
    blocksum_k<<<nb, 256, 0, stream>>>(deg, bsum, N);
    scanb_k<<<1, 256, 0, stream>>>(bsum, boff, nb);
    scanfin_k<<<nb, 256, 0, stream>>>(deg, boff, start, N, E);
    hipMemsetAsync(fill, 0, (size_t)N * 4, stream);
    csr_fill<<<(E + 255) / 256, 256, 0, stream>>>(esrc, edst, dis, start, fill, csrs, csrn, E);

    // 3. GCN layer 1  (bufX -> fp8 bufH8 -> bf16 bufG)
    const int nTilesM = (N + 127) / 128;
    const int nTilesN = D / 128;             // 6
    const int gemmWG  = nTilesM * nTilesN;
    gemm_bf16<true><<<gemmWG, 256, 0, stream>>>(bufX, W1t, bufH8, N, nTilesN);
    agg_fp8<<<(N + 3) / 4, 256, 0, stream>>>(bufH8, bufG, start, csrs, csrn, dis, b1, 1, N);

    // 4. GCN layer 2  (bufG -> fp8 bufH8 -> bf16 bufG)   [bufX stays = x bf16]
    gemm_bf16<true><<<gemmWG, 256, 0, stream>>>(bufG, W2t, bufH8, N, nTilesN);
    agg_fp8<<<(N + 3) / 4, 256, 0, stream>>>(bufH8, bufG, start, csrs, csrn, dis, b2, 0, N);

    // 5. retrieval: bf16 MFMA approx scores -> chunked top-CPC filter -> exact fp32 rescore -> exact top-K
    mfma_bert<<<(N + 127) / 128, 256, 0, stream>>>(Qb, bufX, sparse, sweight, approxScore, B, N);
    int chunk = (N + FCH - 1) / FCH;
    dim3 fgrid(FCH, B);
    filter_topc<<<fgrid, 256, (size_t)chunk * 4, stream>>>(approxScore, candIdx, N, chunk);
    dim3 rgrid(NCAND / 64, B);
    rescore_kernel<<<rgrid, 256, 0, stream>>>(q_emb, x_emb, sparse, sweight, candIdx, resVal, N);
    select_topk<<<B, 256, 0, stream>>>(resVal, candIdx, q_idx, candBuf, outIdx, K);

    // 6. final scoring head  (embeddings now in bufG)
    final_kernel<<<(B * K + 3) / 4, 256, 0, stream>>>(bufG, q_emb, candBuf, scoreW, scoreB, outScore, B, K);
}